// Round 6
// baseline (94.551 us; speedup 1.0000x reference)
//
#include <hip/hip_runtime.h>

#define B_   4
#define LQ_  256
#define LK_  512
#define DIN_ 512
#define H_   256
#define DV_  512

// 2*log2(e): folded into projections so tanh(x) = 1 - 2*rcp(exp2(x')+1), x'=2x*log2e
#define TANH_SCALE 2.885390081777927f

// =====================================================================
// Kernel A: projections. 4 rows/block, thread = h column. No LDS:
// X row data is wave-uniform -> compiler emits scalar (s_load_dwordx4)
// loads, broadcast free. 16 W vector loads in flight per d-group.
//  q blocks -> qT[b][h][i]  (transposed, scaled)
//  k blocks -> kp[b][j][h]  (row-major, scaled; coalesced stores)
// K blocks with rows >= valid_len exit (rows never read downstream).
// =====================================================================
__global__ __launch_bounds__(256) void proj_kernel(
    const float* __restrict__ Q, const float* __restrict__ K,
    const float* __restrict__ Wq, const float* __restrict__ Wk,
    const float* __restrict__ wv, const int* __restrict__ valid_lens,
    float* __restrict__ qT, float* __restrict__ kp, float* __restrict__ wsum) {
  const int blk = blockIdx.x;
  const bool isQ = blk < (B_ * LQ_ / 4);
  const int flat = (isQ ? blk : blk - B_ * LQ_ / 4) * 4;   // flat row
  const int b    = isQ ? (flat >> 8) : (flat >> 9);
  const int rloc = isQ ? (flat & (LQ_ - 1)) : (flat & (LK_ - 1));
  if (!isQ && rloc >= valid_lens[b]) return;

  const float* __restrict__ X = (isQ ? Q : K) + (size_t)flat * DIN_;
  const float* __restrict__ W = isQ ? Wq : Wk;
  const int t = threadIdx.x;   // h

  float acc[4] = {0.f, 0.f, 0.f, 0.f};
  for (int d = 0; d < DIN_; d += 16) {
    float w[16];
#pragma unroll
    for (int u = 0; u < 16; ++u) w[u] = W[(size_t)(d + u) * H_ + t];  // 16 in flight
#pragma unroll
    for (int r = 0; r < 4; ++r) {
      const float* xr = X + (size_t)r * DIN_ + d;          // uniform -> s_load
      const float4 xa = *(const float4*)(xr);
      const float4 xb = *(const float4*)(xr + 4);
      const float4 xc = *(const float4*)(xr + 8);
      const float4 xd = *(const float4*)(xr + 12);
      acc[r] = fmaf(xa.x, w[0],  acc[r]); acc[r] = fmaf(xa.y, w[1],  acc[r]);
      acc[r] = fmaf(xa.z, w[2],  acc[r]); acc[r] = fmaf(xa.w, w[3],  acc[r]);
      acc[r] = fmaf(xb.x, w[4],  acc[r]); acc[r] = fmaf(xb.y, w[5],  acc[r]);
      acc[r] = fmaf(xb.z, w[6],  acc[r]); acc[r] = fmaf(xb.w, w[7],  acc[r]);
      acc[r] = fmaf(xc.x, w[8],  acc[r]); acc[r] = fmaf(xc.y, w[9],  acc[r]);
      acc[r] = fmaf(xc.z, w[10], acc[r]); acc[r] = fmaf(xc.w, w[11], acc[r]);
      acc[r] = fmaf(xd.x, w[12], acc[r]); acc[r] = fmaf(xd.y, w[13], acc[r]);
      acc[r] = fmaf(xd.z, w[14], acc[r]); acc[r] = fmaf(xd.w, w[15], acc[r]);
    }
  }

  if (isQ) {
    float4 o = {acc[0] * TANH_SCALE, acc[1] * TANH_SCALE,
                acc[2] * TANH_SCALE, acc[3] * TANH_SCALE};
    *(float4*)&qT[((size_t)b * H_ + t) * LQ_ + rloc] = o;   // scattered 16B, 1 MB total
  } else {
#pragma unroll
    for (int r = 0; r < 4; ++r)                             // coalesced over t
      kp[(size_t)(flat + r) * H_ + t] = acc[r] * TANH_SCALE;
  }

  if (blk == 0 && t < 64) {
    float s = wv[t] + wv[t + 64] + wv[t + 128] + wv[t + 192];
#pragma unroll
    for (int off = 32; off; off >>= 1) s += __shfl_xor(s, off);
    if (t == 0) *wsum = s;
  }
}

// =====================================================================
// Kernel B: scoresT[b,j,i] = Wsum - 2*sum_h wv[h]*rcp(1+exp2(qT+kp))
// lane = i (qT coalesced), j uniform per block (kp via scalar loads).
// 2 j-rows per block -> exact masking at 2-row granularity.
// grid = B * LK/2 = 1024 blocks x 256 thr; ~half exit by mask.
// =====================================================================
__global__ __launch_bounds__(256) void scores_kernel(
    const float* __restrict__ qT, const float* __restrict__ kp,
    const float* __restrict__ wv, const float* __restrict__ wsum,
    const int* __restrict__ valid_lens, float* __restrict__ scT) {
  const int blk = blockIdx.x;
  const int b  = blk >> 8;
  const int j0 = (blk & 255) * 2;
  const int vl = valid_lens[b];
  if (j0 >= vl) return;
  const int i = threadIdx.x;

  const float* __restrict__ qcol = qT + (size_t)b * H_ * LQ_ + i;
  const float* __restrict__ k0 = kp + (size_t)(b * LK_ + j0) * H_;   // uniform
  const float* __restrict__ k1 = k0 + H_;                            // uniform
  const float Wsum = *wsum;

  float a0 = 0.f, a1 = 0.f;
  for (int h = 0; h < H_; h += 8) {
    float qv[8];
#pragma unroll
    for (int u = 0; u < 8; ++u) qv[u] = qcol[(size_t)(h + u) * LQ_];  // coalesced
    const float4 ka = *(const float4*)&k0[h];
    const float4 kb = *(const float4*)&k0[h + 4];
    const float4 kc = *(const float4*)&k1[h];
    const float4 kd = *(const float4*)&k1[h + 4];
    const float4 wa = *(const float4*)&wv[h];
    const float4 wb = *(const float4*)&wv[h + 4];
    const float kk0[8] = {ka.x, ka.y, ka.z, ka.w, kb.x, kb.y, kb.z, kb.w};
    const float kk1[8] = {kc.x, kc.y, kc.z, kc.w, kd.x, kd.y, kd.z, kd.w};
    const float ww[8]  = {wa.x, wa.y, wa.z, wa.w, wb.x, wb.y, wb.z, wb.w};
#pragma unroll
    for (int u = 0; u < 8; ++u) {
      a0 = fmaf(ww[u], __builtin_amdgcn_rcpf(exp2f(qv[u] + kk0[u]) + 1.f), a0);
      a1 = fmaf(ww[u], __builtin_amdgcn_rcpf(exp2f(qv[u] + kk1[u]) + 1.f), a1);
    }
  }
  scT[((size_t)b * LK_ + j0) * LQ_ + i]     = fmaf(-2.f, a0, Wsum);  // coalesced
  scT[((size_t)b * LK_ + j0 + 1) * LQ_ + i] = fmaf(-2.f, a1, Wsum);  // (garbage if j0+1>=vl; masked later)
}

// =====================================================================
// Kernel C: masked softmax + AV, TI=4 rows/block, 512 thr.
// scoresT read as one float4 per thread. AV unroll x8.
// =====================================================================
__global__ __launch_bounds__(512) void softmax_av_kernel(
    const float* __restrict__ scT, const float* __restrict__ V,
    const int* __restrict__ valid_lens, float* __restrict__ out) {
  __shared__ float4 p4s[LK_];
  __shared__ float redm[8][4];
  __shared__ float reds[8][4];

  const int blk = blockIdx.x;
  const int b = blk >> 6;
  const int i0 = (blk & 63) * 4;
  const int vl = valid_lens[b];
  const int t = threadIdx.x;        // j
  const int lane = t & 63, wave = t >> 6;

  const bool valid = t < vl;
  float s[4], m[4];
  {
    float4 sv = {-3.0e38f, -3.0e38f, -3.0e38f, -3.0e38f};
    if (valid) sv = *(const float4*)&scT[((size_t)b * LK_ + t) * LQ_ + i0];
    s[0] = sv.x; s[1] = sv.y; s[2] = sv.z; s[3] = sv.w;
#pragma unroll
    for (int ii = 0; ii < 4; ++ii) m[ii] = s[ii];
  }
#pragma unroll
  for (int off = 32; off; off >>= 1)
#pragma unroll
    for (int ii = 0; ii < 4; ++ii) m[ii] = fmaxf(m[ii], __shfl_xor(m[ii], off));
  if (lane == 0)
#pragma unroll
    for (int ii = 0; ii < 4; ++ii) redm[wave][ii] = m[ii];
  __syncthreads();
  float e[4], sum[4];
#pragma unroll
  for (int ii = 0; ii < 4; ++ii) {
    float mx = redm[0][ii];
#pragma unroll
    for (int w = 1; w < 8; ++w) mx = fmaxf(mx, redm[w][ii]);
    e[ii] = valid ? __expf(s[ii] - mx) : 0.f;
    sum[ii] = e[ii];
  }
#pragma unroll
  for (int off = 32; off; off >>= 1)
#pragma unroll
    for (int ii = 0; ii < 4; ++ii) sum[ii] += __shfl_xor(sum[ii], off);
  if (lane == 0)
#pragma unroll
    for (int ii = 0; ii < 4; ++ii) reds[wave][ii] = sum[ii];
  __syncthreads();
  {
    float4 pv;
    float tot[4];
#pragma unroll
    for (int ii = 0; ii < 4; ++ii) {
      tot[ii] = reds[0][ii];
#pragma unroll
      for (int w = 1; w < 8; ++w) tot[ii] += reds[w][ii];
    }
    pv.x = e[0] * __builtin_amdgcn_rcpf(tot[0]);
    pv.y = e[1] * __builtin_amdgcn_rcpf(tot[1]);
    pv.z = e[2] * __builtin_amdgcn_rcpf(tot[2]);
    pv.w = e[3] * __builtin_amdgcn_rcpf(tot[3]);
    p4s[t] = pv;
  }
  __syncthreads();

  const float* __restrict__ Vb = V + (size_t)b * LK_ * DV_ + t;
  float a[4] = {0.f, 0.f, 0.f, 0.f};
  int j = 0;
  const int jv = vl & ~7;
  for (; j < jv; j += 8) {
    float v[8];
#pragma unroll
    for (int u = 0; u < 8; ++u) v[u] = Vb[(size_t)(j + u) * DV_];
#pragma unroll
    for (int u = 0; u < 8; ++u) {
      const float4 pp = p4s[j + u];
      a[0] = fmaf(pp.x, v[u], a[0]); a[1] = fmaf(pp.y, v[u], a[1]);
      a[2] = fmaf(pp.z, v[u], a[2]); a[3] = fmaf(pp.w, v[u], a[3]);
    }
  }
  for (; j < vl; ++j) {
    const float v = Vb[(size_t)j * DV_];
    const float4 pp = p4s[j];
    a[0] = fmaf(pp.x, v, a[0]); a[1] = fmaf(pp.y, v, a[1]);
    a[2] = fmaf(pp.z, v, a[2]); a[3] = fmaf(pp.w, v, a[3]);
  }
#pragma unroll
  for (int ii = 0; ii < 4; ++ii)
    out[(size_t)(b * LQ_ + i0 + ii) * DV_ + t] = a[ii];
}

extern "C" void kernel_launch(void* const* d_in, const int* in_sizes, int n_in,
                              void* d_out, int out_size, void* d_ws, size_t ws_size,
                              hipStream_t stream) {
  const float* queries    = (const float*)d_in[0];
  const float* keys       = (const float*)d_in[1];
  const float* values     = (const float*)d_in[2];
  const int*   valid_lens = (const int*)d_in[3];
  const float* Wq         = (const float*)d_in[4];
  const float* Wk         = (const float*)d_in[5];
  const float* wv         = (const float*)d_in[6];
  float* out = (float*)d_out;

  char* ws = (char*)d_ws;
  float* qT   = (float*)ws;                          // B*H*LQ  = 1 MB
  float* kp   = (float*)(ws + (size_t)(1 << 20));    // B*LK*H  = 2 MB
  float* scT  = (float*)(ws + (size_t)(3 << 20));    // B*LK*LQ = 2 MB
  float* wsum = (float*)(ws + (size_t)(5 << 20));    // 4 B

  proj_kernel<<<(B_ * LQ_ + B_ * LK_) / 4, 256, 0, stream>>>(
      queries, keys, Wq, Wk, wv, valid_lens, qT, kp, wsum);
  scores_kernel<<<B_ * (LK_ / 2), 256, 0, stream>>>(
      qT, kp, wv, wsum, valid_lens, scT);
  softmax_av_kernel<<<B_ * (LQ_ / 4), 512, 0, stream>>>(
      scT, values, valid_lens, out);
}